// Round 1
// baseline (3554.755 us; speedup 1.0000x reference)
//
#include <hip/hip_runtime.h>
#include <hip/hip_bf16.h>
#include <math.h>

#define DMODEL 1024
#define DSTATE 16
#define DINNER 2048
#define DTRANK 64
#define NB 2
#define LSEQ 1024
#define ROWS (NB*LSEQ)   // 2048

static __device__ __forceinline__ float sigmoidf_(float x){ return 1.f/(1.f+__expf(-x)); }
static __device__ __forceinline__ float softplusf_(float x){ return fmaxf(x,0.f) + log1pf(__expf(-fabsf(x))); }

// ---------------- LayerNorm over last dim (1024), one block per row ----------------
__global__ __launch_bounds__(256) void ln_kernel(const float* __restrict__ x,
    const float* __restrict__ g, const float* __restrict__ b,
    float* __restrict__ out)
{
  int row = blockIdx.x;
  float4 v = ((const float4*)(x + (size_t)row*DMODEL))[threadIdx.x];
  float s  = v.x+v.y+v.z+v.w;
  float s2 = v.x*v.x+v.y*v.y+v.z*v.z+v.w*v.w;
  #pragma unroll
  for (int off=32; off>=1; off>>=1){ s += __shfl_xor(s,off); s2 += __shfl_xor(s2,off); }
  __shared__ float red[8];
  int lane = threadIdx.x & 63, wid = threadIdx.x >> 6;
  if (lane==0){ red[wid]=s; red[4+wid]=s2; }
  __syncthreads();
  float ts  = red[0]+red[1]+red[2]+red[3];
  float ts2 = red[4]+red[5]+red[6]+red[7];
  float mean = ts*(1.f/DMODEL);
  float var  = ts2*(1.f/DMODEL) - mean*mean;
  float rstd = rsqrtf(var + 1e-5f);
  float4 gv = ((const float4*)g)[threadIdx.x];
  float4 bv = ((const float4*)b)[threadIdx.x];
  float4 o;
  o.x=(v.x-mean)*rstd*gv.x+bv.x;
  o.y=(v.y-mean)*rstd*gv.y+bv.y;
  o.z=(v.z-mean)*rstd*gv.z+bv.z;
  o.w=(v.w-mean)*rstd*gv.w+bv.w;
  ((float4*)(out + (size_t)row*DMODEL))[threadIdx.x] = o;
}

// ---------------- Generic fp32 GEMM: C[M,N] = A[M,K] * W[N,K]^T ----------------
// EPI: 0=none, 1=softplus(acc+bias[n]), 2=acc+addsrc[m*ldc+n] (residual)
#define BM 64
#define BN 64
#define BK 16

template<int EPI>
__global__ __launch_bounds__(256) void gemm_kernel(
    const float* __restrict__ A, int lda,
    const float* __restrict__ W, int ldw,
    float* __restrict__ C, int ldc,
    int M, int N, int K,
    const float* __restrict__ bias,
    const float* __restrict__ addsrc)
{
  __shared__ float As[BK][BM+4];
  __shared__ float Ws[BK][BN+4];
  const int tid = threadIdx.x;
  const int m0 = blockIdx.y*BM, n0 = blockIdx.x*BN;
  const int lr = tid >> 2;          // 0..63 tile row
  const int lk = (tid & 3) << 2;    // 0,4,8,12
  const int ty = tid >> 4, tx = tid & 15;
  float acc[4][4] = {};

  for (int k0 = 0; k0 < K; k0 += BK) {
    float4 av = make_float4(0,0,0,0), wv = make_float4(0,0,0,0);
    int m = m0 + lr;
    if (m < M) av = *(const float4*)(A + (size_t)m*lda + k0 + lk);
    int n = n0 + lr;
    if (n < N) wv = *(const float4*)(W + (size_t)n*ldw + k0 + lk);
    __syncthreads();   // previous iter's compute done before overwrite
    As[lk+0][lr]=av.x; As[lk+1][lr]=av.y; As[lk+2][lr]=av.z; As[lk+3][lr]=av.w;
    Ws[lk+0][lr]=wv.x; Ws[lk+1][lr]=wv.y; Ws[lk+2][lr]=wv.z; Ws[lk+3][lr]=wv.w;
    __syncthreads();
    #pragma unroll
    for (int kk=0; kk<BK; ++kk) {
      float4 a  = *(const float4*)&As[kk][ty<<2];
      float4 bb = *(const float4*)&Ws[kk][tx<<2];
      float aa[4]  = {a.x,a.y,a.z,a.w};
      float bv4[4] = {bb.x,bb.y,bb.z,bb.w};
      #pragma unroll
      for (int i=0;i<4;i++)
        #pragma unroll
        for (int j=0;j<4;j++)
          acc[i][j] = fmaf(aa[i], bv4[j], acc[i][j]);
    }
  }

  #pragma unroll
  for (int i=0;i<4;i++){
    int m = m0 + (ty<<2) + i;
    if (m >= M) continue;
    #pragma unroll
    for (int j=0;j<4;j++){
      int n = n0 + (tx<<2) + j;
      if (n >= N) continue;
      float v = acc[i][j];
      if (EPI==1) v = softplusf_(v + bias[n]);
      if (EPI==2) v += addsrc[(size_t)m*ldc + n];
      C[(size_t)m*ldc + n] = v;
    }
  }
}

// ---------- causal depthwise conv (width 4) + bias + SiLU; u_pre = xz[:, :2048] ----------
__global__ __launch_bounds__(256) void conv_silu_kernel(
    const float* __restrict__ xz, const float* __restrict__ cw,
    const float* __restrict__ cb, float* __restrict__ u)
{
  int idx = blockIdx.x*256 + threadIdx.x;     // B*L*DINNER threads
  int d  = idx & (DINNER-1);
  int bl = idx >> 11;
  int l  = bl & (LSEQ-1);
  const float* col = xz + (size_t)bl*(2*DINNER) + d;
  float w0=cw[d*4+0], w1=cw[d*4+1], w2=cw[d*4+2], w3=cw[d*4+3];
  float x3 = col[0];
  float x2 = (l>=1) ? col[-(ptrdiff_t)(2*DINNER)]  : 0.f;
  float x1 = (l>=2) ? col[-(ptrdiff_t)(4*DINNER)]  : 0.f;
  float x0 = (l>=3) ? col[-(ptrdiff_t)(6*DINNER)]  : 0.f;
  float acc = cb[d] + w0*x0 + w1*x1 + w2*x2 + w3*x3;
  u[(size_t)bl*DINNER + d] = acc * sigmoidf_(acc);
}

// ---------------- selective scan: one thread per (b, d), 16 states in regs ----------------
// ys written in-place over delta (each element read-then-written once by its own thread).
__global__ __launch_bounds__(256) void scan_kernel(
    const float* delta, float* ys,
    const float* __restrict__ u,
    const float* __restrict__ xz,     // res at [row][2048+d], stride 4096
    const float* __restrict__ xdbl,   // [row][96]: dt 0..63, B 64..79, C 80..95
    const float* __restrict__ A_log,  // [DINNER][16]
    const float* __restrict__ Dp)
{
  int gid = blockIdx.x*256 + threadIdx.x;   // 0..4095
  int d = gid & (DINNER-1);
  int b = gid >> 11;
  float A[DSTATE];
  #pragma unroll
  for (int s=0;s<DSTATE;s++) A[s] = -__expf(A_log[d*DSTATE+s]);
  float Dpd = Dp[d];
  float h[DSTATE] = {};
  const float* drow = delta + (size_t)b*LSEQ*DINNER + d;
  const float* urow = u     + (size_t)b*LSEQ*DINNER + d;
  const float* rrow = xz    + (size_t)b*LSEQ*2*DINNER + DINNER + d;
  const float* xrow = xdbl  + (size_t)b*LSEQ*96;
  float* yrow = ys + (size_t)b*LSEQ*DINNER + d;
  for (int l=0; l<LSEQ; ++l) {
    float dv = drow[(size_t)l*DINNER];
    float uv = urow[(size_t)l*DINNER];
    float rv = rrow[(size_t)l*2*DINNER];
    const float* bc = xrow + l*96 + DTRANK;   // B at bc[0..15], C at bc[16..31]
    float du = dv*uv;
    float y = 0.f;
    #pragma unroll
    for (int s=0;s<DSTATE;s++){
      float dA = __expf(dv*A[s]);
      h[s] = dA*h[s] + du*bc[s];
      y += h[s]*bc[DSTATE+s];
    }
    y = (y + uv*Dpd) * (rv * sigmoidf_(rv));
    yrow[(size_t)l*DINNER] = y;
  }
}

extern "C" void kernel_launch(void* const* d_in, const int* in_sizes, int n_in,
                              void* d_out, int out_size, void* d_ws, size_t ws_size,
                              hipStream_t stream)
{
  const float* x      = (const float*)d_in[0];
  const float* ln_g   = (const float*)d_in[1];
  const float* ln_b   = (const float*)d_in[2];
  const float* in_w   = (const float*)d_in[3];
  const float* conv_w = (const float*)d_in[4];
  const float* conv_b = (const float*)d_in[5];
  const float* xp_w   = (const float*)d_in[6];
  const float* dt_w   = (const float*)d_in[7];
  const float* dt_b   = (const float*)d_in[8];
  const float* A_log  = (const float*)d_in[9];
  const float* Dp     = (const float*)d_in[10];
  const float* out_w  = (const float*)d_in[11];
  const float* fn_g   = (const float*)d_in[12];
  const float* fn_b   = (const float*)d_in[13];
  float* out = (float*)d_out;

  float* ws    = (float*)d_ws;
  float* x_cur = ws;  ws += (size_t)ROWS*DMODEL;          // 8 MB
  float* xn    = ws;  ws += (size_t)ROWS*DMODEL;          // 8 MB
  float* xz    = ws;  ws += (size_t)ROWS*2*DINNER;        // 32 MB
  float* ubuf  = ws;  ws += (size_t)ROWS*DINNER;          // 16 MB
  float* xdbl  = ws;  ws += (size_t)ROWS*96;              // 0.75 MB
  float* delta = ws;  ws += (size_t)ROWS*DINNER;          // 16 MB (ys in-place)

  for (int layer=0; layer<2; ++layer) {
    const float* xin = (layer==0) ? x : x_cur;
    ln_kernel<<<ROWS,256,0,stream>>>(xin, ln_g+layer*DMODEL, ln_b+layer*DMODEL, xn);
    // xz = xn @ in_w^T   [2048 x 4096], K=1024
    gemm_kernel<0><<<dim3(2*DINNER/BN, ROWS/BM),256,0,stream>>>(
        xn, DMODEL, in_w + (size_t)layer*2*DINNER*DMODEL, DMODEL,
        xz, 2*DINNER, ROWS, 2*DINNER, DMODEL, nullptr, nullptr);
    // u = silu(causal_conv(xz[:, :2048]) + cb)
    conv_silu_kernel<<<(ROWS*DINNER)/256,256,0,stream>>>(
        xz, conv_w + (size_t)layer*DINNER*4, conv_b + (size_t)layer*DINNER, ubuf);
    // xdbl = u @ xp_w^T   [2048 x 96], K=2048
    gemm_kernel<0><<<dim3((96+BN-1)/BN, ROWS/BM),256,0,stream>>>(
        ubuf, DINNER, xp_w + (size_t)layer*96*DINNER, DINNER,
        xdbl, 96, ROWS, 96, DINNER, nullptr, nullptr);
    // delta = softplus(xdbl[:, :64] @ dt_w^T + dt_b)   [2048 x 2048], K=64
    gemm_kernel<1><<<dim3(DINNER/BN, ROWS/BM),256,0,stream>>>(
        xdbl, 96, dt_w + (size_t)layer*DINNER*DTRANK, DTRANK,
        delta, DINNER, ROWS, DINNER, DTRANK,
        dt_b + (size_t)layer*DINNER, nullptr);
    // selective scan (writes ys in place of delta), fused +u*Dp and *silu(res)
    scan_kernel<<<(NB*DINNER)/256,256,0,stream>>>(
        delta, delta, ubuf, xz, xdbl,
        A_log + (size_t)layer*DINNER*DSTATE, Dp + (size_t)layer*DINNER);
    // x_cur = xin + ys @ out_w^T   [2048 x 1024], K=2048
    gemm_kernel<2><<<dim3(DMODEL/BN, ROWS/BM),256,0,stream>>>(
        delta, DINNER, out_w + (size_t)layer*DMODEL*DINNER, DINNER,
        x_cur, DMODEL, ROWS, DMODEL, DINNER, nullptr, xin);
  }
  ln_kernel<<<ROWS,256,0,stream>>>(x_cur, fn_g, fn_b, out);
}

// Round 2
// 1263.715 us; speedup vs baseline: 2.8129x; 2.8129x over previous
//
#include <hip/hip_runtime.h>
#include <hip/hip_bf16.h>
#include <math.h>

#define DMODEL 1024
#define DSTATE 16
#define DINNER 2048
#define DTRANK 64
#define NB 2
#define LSEQ 1024
#define ROWS (NB*LSEQ)   // 2048
#define NCH 64           // chunks per sequence
#define LCH (LSEQ/NCH)   // 16 steps per chunk

static __device__ __forceinline__ float sigmoidf_(float x){ return 1.f/(1.f+__expf(-x)); }
static __device__ __forceinline__ float softplusf_(float x){ return fmaxf(x,0.f) + log1pf(__expf(-fabsf(x))); }

// ---------------- LayerNorm over last dim (1024), one block per row ----------------
__global__ __launch_bounds__(256) void ln_kernel(const float* __restrict__ x,
    const float* __restrict__ g, const float* __restrict__ b,
    float* __restrict__ out)
{
  int row = blockIdx.x;
  float4 v = ((const float4*)(x + (size_t)row*DMODEL))[threadIdx.x];
  float s  = v.x+v.y+v.z+v.w;
  float s2 = v.x*v.x+v.y*v.y+v.z*v.z+v.w*v.w;
  #pragma unroll
  for (int off=32; off>=1; off>>=1){ s += __shfl_xor(s,off); s2 += __shfl_xor(s2,off); }
  __shared__ float red[8];
  int lane = threadIdx.x & 63, wid = threadIdx.x >> 6;
  if (lane==0){ red[wid]=s; red[4+wid]=s2; }
  __syncthreads();
  float ts  = red[0]+red[1]+red[2]+red[3];
  float ts2 = red[4]+red[5]+red[6]+red[7];
  float mean = ts*(1.f/DMODEL);
  float var  = ts2*(1.f/DMODEL) - mean*mean;
  float rstd = rsqrtf(var + 1e-5f);
  float4 gv = ((const float4*)g)[threadIdx.x];
  float4 bv = ((const float4*)b)[threadIdx.x];
  float4 o;
  o.x=(v.x-mean)*rstd*gv.x+bv.x;
  o.y=(v.y-mean)*rstd*gv.y+bv.y;
  o.z=(v.z-mean)*rstd*gv.z+bv.z;
  o.w=(v.w-mean)*rstd*gv.w+bv.w;
  ((float4*)(out + (size_t)row*DMODEL))[threadIdx.x] = o;
}

// ---------------- Generic fp32 GEMM: C[M,N] = A[M,K] * W[N,K]^T ----------------
// EPI: 0=none, 1=softplus(acc+bias[n]), 2=acc+addsrc[m*ldc+n] (residual)
#define BM 64
#define BN 64
#define BK 16

template<int EPI>
__global__ __launch_bounds__(256) void gemm_kernel(
    const float* __restrict__ A, int lda,
    const float* __restrict__ W, int ldw,
    float* __restrict__ C, int ldc,
    int M, int N, int K,
    const float* __restrict__ bias,
    const float* __restrict__ addsrc)
{
  __shared__ float As[BK][BM+4];
  __shared__ float Ws[BK][BN+4];
  const int tid = threadIdx.x;
  const int m0 = blockIdx.y*BM, n0 = blockIdx.x*BN;
  const int lr = tid >> 2;          // 0..63 tile row
  const int lk = (tid & 3) << 2;    // 0,4,8,12
  const int ty = tid >> 4, tx = tid & 15;
  float acc[4][4] = {};

  for (int k0 = 0; k0 < K; k0 += BK) {
    float4 av = make_float4(0,0,0,0), wv = make_float4(0,0,0,0);
    int m = m0 + lr;
    if (m < M) av = *(const float4*)(A + (size_t)m*lda + k0 + lk);
    int n = n0 + lr;
    if (n < N) wv = *(const float4*)(W + (size_t)n*ldw + k0 + lk);
    __syncthreads();   // previous iter's compute done before overwrite
    As[lk+0][lr]=av.x; As[lk+1][lr]=av.y; As[lk+2][lr]=av.z; As[lk+3][lr]=av.w;
    Ws[lk+0][lr]=wv.x; Ws[lk+1][lr]=wv.y; Ws[lk+2][lr]=wv.z; Ws[lk+3][lr]=wv.w;
    __syncthreads();
    #pragma unroll
    for (int kk=0; kk<BK; ++kk) {
      float4 a  = *(const float4*)&As[kk][ty<<2];
      float4 bb = *(const float4*)&Ws[kk][tx<<2];
      float aa[4]  = {a.x,a.y,a.z,a.w};
      float bv4[4] = {bb.x,bb.y,bb.z,bb.w};
      #pragma unroll
      for (int i=0;i<4;i++)
        #pragma unroll
        for (int j=0;j<4;j++)
          acc[i][j] = fmaf(aa[i], bv4[j], acc[i][j]);
    }
  }

  #pragma unroll
  for (int i=0;i<4;i++){
    int m = m0 + (ty<<2) + i;
    if (m >= M) continue;
    #pragma unroll
    for (int j=0;j<4;j++){
      int n = n0 + (tx<<2) + j;
      if (n >= N) continue;
      float v = acc[i][j];
      if (EPI==1) v = softplusf_(v + bias[n]);
      if (EPI==2) v += addsrc[(size_t)m*ldc + n];
      C[(size_t)m*ldc + n] = v;
    }
  }
}

// ---------- causal depthwise conv (width 4) + bias + SiLU; u_pre = xz[:, :2048] ----------
__global__ __launch_bounds__(256) void conv_silu_kernel(
    const float* __restrict__ xz, const float* __restrict__ cw,
    const float* __restrict__ cb, float* __restrict__ u)
{
  int idx = blockIdx.x*256 + threadIdx.x;     // B*L*DINNER threads
  int d  = idx & (DINNER-1);
  int bl = idx >> 11;
  int l  = bl & (LSEQ-1);
  const float* col = xz + (size_t)bl*(2*DINNER) + d;
  float w0=cw[d*4+0], w1=cw[d*4+1], w2=cw[d*4+2], w3=cw[d*4+3];
  float x3 = col[0];
  float x2 = (l>=1) ? col[-(ptrdiff_t)(2*DINNER)]  : 0.f;
  float x1 = (l>=2) ? col[-(ptrdiff_t)(4*DINNER)]  : 0.f;
  float x0 = (l>=3) ? col[-(ptrdiff_t)(6*DINNER)]  : 0.f;
  float acc = cb[d] + w0*x0 + w1*x1 + w2*x2 + w3*x3;
  u[(size_t)bl*DINNER + d] = acc * sigmoidf_(acc);
}

// ======================= chunked selective scan =======================
// Recurrence per (b,d,s): h[l] = exp(delta[l]*A[s])*h[l-1] + delta[l]*u[l]*B[l][s]
// Chunk decay: prod_l exp(delta*A) = exp(A * sum_l delta)

// Phase 1: per (b,d,chunk) local scan with h0=0 -> hout[b][c][d][16], sumd[b][c][d]
__global__ __launch_bounds__(256) void scan_phase1(
    const float* __restrict__ delta, const float* __restrict__ u,
    const float* __restrict__ xdbl, const float* __restrict__ A_log,
    float* __restrict__ hout, float* __restrict__ sumd)
{
  int gid = blockIdx.x*256 + threadIdx.x;     // B*NCH*DINNER
  int d = gid & (DINNER-1);
  int c = (gid >> 11) & (NCH-1);
  int b = gid >> 17;
  float A[DSTATE];
  #pragma unroll
  for (int s=0;s<DSTATE;s++) A[s] = -__expf(A_log[d*DSTATE+s]);
  int l0 = c*LCH;
  const float* drow = delta + ((size_t)(b*LSEQ + l0))*DINNER + d;
  const float* urow = u     + ((size_t)(b*LSEQ + l0))*DINNER + d;
  const float* xrow = xdbl  + ((size_t)(b*LSEQ + l0))*96 + DTRANK;   // B at [0..15]
  float h[DSTATE] = {};
  float sd = 0.f;
  for (int l=0; l<LCH; ++l) {
    float dv = drow[(size_t)l*DINNER];
    float uv = urow[(size_t)l*DINNER];
    const float* bc = xrow + l*96;
    float du = dv*uv;
    sd += dv;
    #pragma unroll
    for (int s=0;s<DSTATE;s++)
      h[s] = __expf(dv*A[s])*h[s] + du*bc[s];
  }
  float* hp = hout + (((size_t)(b*NCH + c))*DINNER + d)*DSTATE;
  #pragma unroll
  for (int q=0;q<4;q++)
    ((float4*)hp)[q] = make_float4(h[4*q],h[4*q+1],h[4*q+2],h[4*q+3]);
  sumd[((size_t)(b*NCH + c))*DINNER + d] = sd;
}

// Phase 2: per (b,d,s) compose over chunks; hout is overwritten IN PLACE with hin
__global__ __launch_bounds__(256) void scan_phase2(
    float* __restrict__ hout, const float* __restrict__ sumd,
    const float* __restrict__ A_log)
{
  int gid = blockIdx.x*256 + threadIdx.x;     // B*DINNER*DSTATE = 65536
  int s = gid & (DSTATE-1);
  int d = (gid >> 4) & (DINNER-1);
  int b = gid >> 15;
  float A = -__expf(A_log[d*DSTATE+s]);
  float h = 0.f;
  for (int c=0; c<NCH; ++c) {
    size_t hi = (((size_t)(b*NCH + c))*DINNER + d)*DSTATE + s;
    float tmp = hout[hi];
    hout[hi] = h;                              // hin for chunk c
    float P = __expf(A * sumd[((size_t)(b*NCH + c))*DINNER + d]);
    h = P*h + tmp;
  }
}

// Phase 3: per (b,d,chunk) rescan with correct hin; fused epilogue; ys -> out buffer
__global__ __launch_bounds__(256) void scan_phase3(
    const float* __restrict__ delta, float* __restrict__ ys,
    const float* __restrict__ u,
    const float* __restrict__ xz,     // res at [row][2048+d], stride 4096
    const float* __restrict__ xdbl,   // [row][96]: dt 0..63, B 64..79, C 80..95
    const float* __restrict__ A_log,
    const float* __restrict__ Dp,
    const float* __restrict__ hin)
{
  int gid = blockIdx.x*256 + threadIdx.x;     // B*NCH*DINNER
  int d = gid & (DINNER-1);
  int c = (gid >> 11) & (NCH-1);
  int b = gid >> 17;
  float A[DSTATE];
  #pragma unroll
  for (int s=0;s<DSTATE;s++) A[s] = -__expf(A_log[d*DSTATE+s]);
  float Dpd = Dp[d];
  float h[DSTATE];
  const float* hp = hin + (((size_t)(b*NCH + c))*DINNER + d)*DSTATE;
  #pragma unroll
  for (int q=0;q<4;q++){
    float4 hv = ((const float4*)hp)[q];
    h[4*q]=hv.x; h[4*q+1]=hv.y; h[4*q+2]=hv.z; h[4*q+3]=hv.w;
  }
  int l0 = c*LCH;
  const float* drow = delta + ((size_t)(b*LSEQ + l0))*DINNER + d;
  const float* urow = u     + ((size_t)(b*LSEQ + l0))*DINNER + d;
  const float* rrow = xz    + ((size_t)(b*LSEQ + l0))*2*DINNER + DINNER + d;
  const float* xrow = xdbl  + ((size_t)(b*LSEQ + l0))*96 + DTRANK;
  float* yrow = ys + ((size_t)(b*LSEQ + l0))*DINNER + d;
  for (int l=0; l<LCH; ++l) {
    float dv = drow[(size_t)l*DINNER];
    float uv = urow[(size_t)l*DINNER];
    float rv = rrow[(size_t)l*2*DINNER];
    const float* bc = xrow + l*96;            // B at [0..15], C at [16..31]
    float du = dv*uv;
    float y = 0.f;
    #pragma unroll
    for (int s=0;s<DSTATE;s++){
      float dA = __expf(dv*A[s]);
      h[s] = dA*h[s] + du*bc[s];
      y += h[s]*bc[DSTATE+s];
    }
    y = (y + uv*Dpd) * (rv * sigmoidf_(rv));
    yrow[(size_t)l*DINNER] = y;
  }
}

extern "C" void kernel_launch(void* const* d_in, const int* in_sizes, int n_in,
                              void* d_out, int out_size, void* d_ws, size_t ws_size,
                              hipStream_t stream)
{
  const float* x      = (const float*)d_in[0];
  const float* ln_g   = (const float*)d_in[1];
  const float* ln_b   = (const float*)d_in[2];
  const float* in_w   = (const float*)d_in[3];
  const float* conv_w = (const float*)d_in[4];
  const float* conv_b = (const float*)d_in[5];
  const float* xp_w   = (const float*)d_in[6];
  const float* dt_w   = (const float*)d_in[7];
  const float* dt_b   = (const float*)d_in[8];
  const float* A_log  = (const float*)d_in[9];
  const float* Dp     = (const float*)d_in[10];
  const float* out_w  = (const float*)d_in[11];
  const float* fn_g   = (const float*)d_in[12];
  const float* fn_b   = (const float*)d_in[13];
  float* out = (float*)d_out;

  float* ws    = (float*)d_ws;
  float* x_cur = ws;  ws += (size_t)ROWS*DMODEL;          // 8 MB
  float* xn    = ws;  ws += (size_t)ROWS*DMODEL;          // 8 MB
  float* xz    = ws;  ws += (size_t)ROWS*2*DINNER;        // 32 MB
  float* ubuf  = ws;  ws += (size_t)ROWS*DINNER;          // 16 MB
  float* xdbl  = ws;  ws += (size_t)ROWS*96;              // 0.75 MB
  float* delta = ws;  ws += (size_t)ROWS*DINNER;          // 16 MB (ys in-place)
  float* hout  = ws;  ws += (size_t)NB*NCH*DINNER*DSTATE; // 16 MB
  float* sumd  = ws;  ws += (size_t)NB*NCH*DINNER;        // 1 MB

  for (int layer=0; layer<2; ++layer) {
    const float* xin = (layer==0) ? x : x_cur;
    const float* Al  = A_log + (size_t)layer*DINNER*DSTATE;
    ln_kernel<<<ROWS,256,0,stream>>>(xin, ln_g+layer*DMODEL, ln_b+layer*DMODEL, xn);
    // xz = xn @ in_w^T   [2048 x 4096], K=1024
    gemm_kernel<0><<<dim3(2*DINNER/BN, ROWS/BM),256,0,stream>>>(
        xn, DMODEL, in_w + (size_t)layer*2*DINNER*DMODEL, DMODEL,
        xz, 2*DINNER, ROWS, 2*DINNER, DMODEL, nullptr, nullptr);
    // u = silu(causal_conv(xz[:, :2048]) + cb)
    conv_silu_kernel<<<(ROWS*DINNER)/256,256,0,stream>>>(
        xz, conv_w + (size_t)layer*DINNER*4, conv_b + (size_t)layer*DINNER, ubuf);
    // xdbl = u @ xp_w^T   [2048 x 96], K=2048
    gemm_kernel<0><<<dim3((96+BN-1)/BN, ROWS/BM),256,0,stream>>>(
        ubuf, DINNER, xp_w + (size_t)layer*96*DINNER, DINNER,
        xdbl, 96, ROWS, 96, DINNER, nullptr, nullptr);
    // delta = softplus(xdbl[:, :64] @ dt_w^T + dt_b)   [2048 x 2048], K=64
    gemm_kernel<1><<<dim3(DINNER/BN, ROWS/BM),256,0,stream>>>(
        xdbl, 96, dt_w + (size_t)layer*DINNER*DTRANK, DTRANK,
        delta, DINNER, ROWS, DINNER, DTRANK,
        dt_b + (size_t)layer*DINNER, nullptr);
    // chunked selective scan (ys written in place of delta)
    scan_phase1<<<(NB*NCH*DINNER)/256,256,0,stream>>>(
        delta, ubuf, xdbl, Al, hout, sumd);
    scan_phase2<<<(NB*DINNER*DSTATE)/256,256,0,stream>>>(hout, sumd, Al);
    scan_phase3<<<(NB*NCH*DINNER)/256,256,0,stream>>>(
        delta, delta, ubuf, xz, xdbl, Al, Dp + (size_t)layer*DINNER, hout);
    // x_cur = xin + ys @ out_w^T   [2048 x 1024], K=2048
    gemm_kernel<2><<<dim3(DMODEL/BN, ROWS/BM),256,0,stream>>>(
        delta, DINNER, out_w + (size_t)layer*DMODEL*DINNER, DINNER,
        x_cur, DMODEL, ROWS, DMODEL, DINNER, nullptr, xin);
  }
  ln_kernel<<<ROWS,256,0,stream>>>(x_cur, fn_g, fn_b, out);
}

// Round 3
// 541.231 us; speedup vs baseline: 6.5679x; 2.3349x over previous
//
#include <hip/hip_runtime.h>
#include <hip/hip_bf16.h>
#include <math.h>
#include <stdint.h>

#define DMODEL 1024
#define DSTATE 16
#define DINNER 2048
#define DTRANK 64
#define NB 2
#define LSEQ 1024
#define ROWS (NB*LSEQ)   // 2048
#define NCH 64           // chunks per sequence
#define LCH (LSEQ/NCH)   // 16 steps per chunk

typedef __bf16 bf16_t;
typedef __bf16 bf16x8 __attribute__((ext_vector_type(8)));
typedef __bf16 bf16x4 __attribute__((ext_vector_type(4)));
typedef float  f32x4  __attribute__((ext_vector_type(4)));

#define AS1(p) ((const __attribute__((address_space(1))) void*)(p))
#define AS3(p) ((__attribute__((address_space(3))) void*)(uint32_t)(uintptr_t)(p))

static __device__ __forceinline__ float sigmoidf_(float x){ return 1.f/(1.f+__expf(-x)); }
static __device__ __forceinline__ float softplusf_(float x){ return fmaxf(x,0.f) + log1pf(__expf(-fabsf(x))); }

// ---------------- f32 -> bf16 conversion (weights) ----------------
__global__ __launch_bounds__(256) void cvt_kernel(const float* __restrict__ in,
    bf16_t* __restrict__ out, int n4)
{
  int i = blockIdx.x*256 + threadIdx.x;
  if (i < n4){
    float4 v = ((const float4*)in)[i];
    bf16x4 o = { (bf16_t)v.x, (bf16_t)v.y, (bf16_t)v.z, (bf16_t)v.w };
    ((bf16x4*)out)[i] = o;
  }
}

// ---------------- LayerNorm over last dim (1024), one block per row ----------------
// OUTBF=1: write bf16 (for GEMM input); OUTBF=0: write fp32 (final LN)
template<int OUTBF>
__global__ __launch_bounds__(256) void ln_kernel(const float* __restrict__ x,
    const float* __restrict__ g, const float* __restrict__ b,
    float* __restrict__ outf, bf16_t* __restrict__ outb)
{
  int row = blockIdx.x;
  float4 v = ((const float4*)(x + (size_t)row*DMODEL))[threadIdx.x];
  float s  = v.x+v.y+v.z+v.w;
  float s2 = v.x*v.x+v.y*v.y+v.z*v.z+v.w*v.w;
  #pragma unroll
  for (int off=32; off>=1; off>>=1){ s += __shfl_xor(s,off); s2 += __shfl_xor(s2,off); }
  __shared__ float red[8];
  int lane = threadIdx.x & 63, wid = threadIdx.x >> 6;
  if (lane==0){ red[wid]=s; red[4+wid]=s2; }
  __syncthreads();
  float ts  = red[0]+red[1]+red[2]+red[3];
  float ts2 = red[4]+red[5]+red[6]+red[7];
  float mean = ts*(1.f/DMODEL);
  float var  = ts2*(1.f/DMODEL) - mean*mean;
  float rstd = rsqrtf(var + 1e-5f);
  float4 gv = ((const float4*)g)[threadIdx.x];
  float4 bv = ((const float4*)b)[threadIdx.x];
  float4 o;
  o.x=(v.x-mean)*rstd*gv.x+bv.x;
  o.y=(v.y-mean)*rstd*gv.y+bv.y;
  o.z=(v.z-mean)*rstd*gv.z+bv.z;
  o.w=(v.w-mean)*rstd*gv.w+bv.w;
  if (OUTBF){
    bf16x4 ob = { (bf16_t)o.x, (bf16_t)o.y, (bf16_t)o.z, (bf16_t)o.w };
    ((bf16x4*)(outb + (size_t)row*DMODEL))[threadIdx.x] = ob;
  } else {
    ((float4*)(outf + (size_t)row*DMODEL))[threadIdx.x] = o;
  }
}

// ================= bf16 MFMA GEMM: C[M,N] = A[M,K] * W[N,K]^T =================
// 128x128 tile, BK=64, 4 waves (2x2), each wave 64x64 = 4x4 frags of 16x16x32.
// EPI: 0 = fp32 C; 1 = softplus(acc+bias[n]) fp32; 2 = acc+addsrc fp32;
//      3 = fp32 C and bf16 C2 (dual write)
#define GBM 128
#define GBN 128
#define GBK 64

template<int EPI, bool NGUARD>
__global__ __launch_bounds__(256) void gemm_bf16(
    const bf16_t* __restrict__ A, int lda,
    const bf16_t* __restrict__ W, int ldw,
    float* __restrict__ C, int ldc,
    int M, int N, int K,
    const float* __restrict__ bias,
    const float* __restrict__ addsrc,
    bf16_t* __restrict__ C2)
{
  __shared__ __align__(16) char lds[2*GBM*GBK*2];   // 32 KB: sA | sB
  char* sA = lds;
  char* sB = lds + GBM*GBK*2;
  const int tid  = threadIdx.x;
  const int lane = tid & 63, wid = tid >> 6;
  const int wr = wid >> 1, wc = wid & 1;            // 2x2 wave grid
  const int frow = lane & 15, kgrp = lane >> 4;
  const int m0 = blockIdx.y*GBM, n0 = blockIdx.x*GBN;
  // staging geometry: chunk ci covers LDS bytes [ci*1024, ci*1024+1024)
  const int srow  = (lane >> 3);          // 0..7 row within chunk
  const int scolb = (lane & 7) * 16;      // byte offset in K (0..112)

  f32x4 acc[4][4];
  #pragma unroll
  for (int i=0;i<4;i++)
    #pragma unroll
    for (int j=0;j<4;j++)
      acc[i][j] = (f32x4){0.f,0.f,0.f,0.f};

  for (int k0 = 0; k0 < K; k0 += GBK) {
    #pragma unroll
    for (int r=0;r<4;++r){
      int ci  = r*4 + wid;                // 0..15
      int row = ci*8 + srow;              // 0..127
      {
        const char* src = (const char*)A + ((size_t)(m0+row)*lda + k0)*2 + scolb;
        __builtin_amdgcn_global_load_lds(AS1(src), AS3(sA + ci*1024), 16, 0, 0);
      }
      {
        int grow = n0 + row;
        if (NGUARD) grow = (grow < N) ? grow : (N-1);
        const char* src = (const char*)W + ((size_t)grow*ldw + k0)*2 + scolb;
        __builtin_amdgcn_global_load_lds(AS1(src), AS3(sB + ci*1024), 16, 0, 0);
      }
    }
    __syncthreads();   // drains vmcnt (compiler emits waitcnt before barrier)
    #pragma unroll
    for (int ks=0; ks<2; ++ks){
      bf16x8 af[4], bfr[4];
      #pragma unroll
      for (int i=0;i<4;i++)
        af[i] = *(const bf16x8*)(sA + (wr*64 + i*16 + frow)*128 + ks*64 + kgrp*16);
      #pragma unroll
      for (int j=0;j<4;j++)
        bfr[j] = *(const bf16x8*)(sB + (wc*64 + j*16 + frow)*128 + ks*64 + kgrp*16);
      #pragma unroll
      for (int i=0;i<4;i++)
        #pragma unroll
        for (int j=0;j<4;j++)
          acc[i][j] = __builtin_amdgcn_mfma_f32_16x16x32_bf16(af[i], bfr[j], acc[i][j], 0, 0, 0);
    }
    __syncthreads();
  }

  #pragma unroll
  for (int i=0;i<4;i++){
    int rbase = m0 + wr*64 + i*16 + kgrp*4;
    #pragma unroll
    for (int j=0;j<4;j++){
      int col = n0 + wc*64 + j*16 + frow;
      if (NGUARD && col >= N) continue;
      #pragma unroll
      for (int q=0;q<4;q++){
        float v = acc[i][j][q];
        int row = rbase + q;
        if (EPI==1) v = softplusf_(v + bias[col]);
        if (EPI==2) v += addsrc[(size_t)row*ldc + col];
        C[(size_t)row*ldc + col] = v;
        if (EPI==3) C2[(size_t)row*ldc + col] = (bf16_t)v;
      }
    }
  }
}

// ---------- causal depthwise conv (width 4) + bias + SiLU; dual fp32/bf16 out ----------
__global__ __launch_bounds__(256) void conv_silu_kernel(
    const float* __restrict__ xz, const float* __restrict__ cw,
    const float* __restrict__ cb, float* __restrict__ u, bf16_t* __restrict__ ub)
{
  int idx = blockIdx.x*256 + threadIdx.x;     // B*L*DINNER threads
  int d  = idx & (DINNER-1);
  int bl = idx >> 11;
  int l  = bl & (LSEQ-1);
  const float* col = xz + (size_t)bl*(2*DINNER) + d;
  float w0=cw[d*4+0], w1=cw[d*4+1], w2=cw[d*4+2], w3=cw[d*4+3];
  float x3 = col[0];
  float x2 = (l>=1) ? col[-(ptrdiff_t)(2*DINNER)]  : 0.f;
  float x1 = (l>=2) ? col[-(ptrdiff_t)(4*DINNER)]  : 0.f;
  float x0 = (l>=3) ? col[-(ptrdiff_t)(6*DINNER)]  : 0.f;
  float acc = cb[d] + w0*x0 + w1*x1 + w2*x2 + w3*x3;
  float uu = acc * sigmoidf_(acc);
  u [(size_t)bl*DINNER + d] = uu;
  ub[(size_t)bl*DINNER + d] = (bf16_t)uu;
}

// ======================= chunked selective scan =======================
__global__ __launch_bounds__(256) void scan_phase1(
    const float* __restrict__ delta, const float* __restrict__ u,
    const float* __restrict__ xdbl, const float* __restrict__ A_log,
    float* __restrict__ hout, float* __restrict__ sumd)
{
  int gid = blockIdx.x*256 + threadIdx.x;     // B*NCH*DINNER
  int d = gid & (DINNER-1);
  int c = (gid >> 11) & (NCH-1);
  int b = gid >> 17;
  float A[DSTATE];
  #pragma unroll
  for (int s=0;s<DSTATE;s++) A[s] = -__expf(A_log[d*DSTATE+s]);
  int l0 = c*LCH;
  const float* drow = delta + ((size_t)(b*LSEQ + l0))*DINNER + d;
  const float* urow = u     + ((size_t)(b*LSEQ + l0))*DINNER + d;
  const float* xrow = xdbl  + ((size_t)(b*LSEQ + l0))*96 + DTRANK;   // B at [0..15]
  float h[DSTATE] = {};
  float sd = 0.f;
  for (int l=0; l<LCH; ++l) {
    float dv = drow[(size_t)l*DINNER];
    float uv = urow[(size_t)l*DINNER];
    const float* bc = xrow + l*96;
    float du = dv*uv;
    sd += dv;
    #pragma unroll
    for (int s=0;s<DSTATE;s++)
      h[s] = __expf(dv*A[s])*h[s] + du*bc[s];
  }
  float* hp = hout + (((size_t)(b*NCH + c))*DINNER + d)*DSTATE;
  #pragma unroll
  for (int q=0;q<4;q++)
    ((float4*)hp)[q] = make_float4(h[4*q],h[4*q+1],h[4*q+2],h[4*q+3]);
  sumd[((size_t)(b*NCH + c))*DINNER + d] = sd;
}

__global__ __launch_bounds__(256) void scan_phase2(
    float* __restrict__ hout, const float* __restrict__ sumd,
    const float* __restrict__ A_log)
{
  int gid = blockIdx.x*256 + threadIdx.x;     // B*DINNER*DSTATE = 65536
  int s = gid & (DSTATE-1);
  int d = (gid >> 4) & (DINNER-1);
  int b = gid >> 15;
  float A = -__expf(A_log[d*DSTATE+s]);
  float h = 0.f;
  for (int c=0; c<NCH; ++c) {
    size_t hi = (((size_t)(b*NCH + c))*DINNER + d)*DSTATE + s;
    float tmp = hout[hi];
    hout[hi] = h;                              // hin for chunk c
    float P = __expf(A * sumd[((size_t)(b*NCH + c))*DINNER + d]);
    h = P*h + tmp;
  }
}

// Phase 3: rescan with hin; fused epilogue; writes ys as bf16 (out_proj input)
__global__ __launch_bounds__(256) void scan_phase3(
    const float* __restrict__ delta, bf16_t* __restrict__ ysb,
    const float* __restrict__ u,
    const float* __restrict__ xz,     // res at [row][2048+d], stride 4096
    const float* __restrict__ xdbl,   // [row][96]
    const float* __restrict__ A_log,
    const float* __restrict__ Dp,
    const float* __restrict__ hin)
{
  int gid = blockIdx.x*256 + threadIdx.x;     // B*NCH*DINNER
  int d = gid & (DINNER-1);
  int c = (gid >> 11) & (NCH-1);
  int b = gid >> 17;
  float A[DSTATE];
  #pragma unroll
  for (int s=0;s<DSTATE;s++) A[s] = -__expf(A_log[d*DSTATE+s]);
  float Dpd = Dp[d];
  float h[DSTATE];
  const float* hp = hin + (((size_t)(b*NCH + c))*DINNER + d)*DSTATE;
  #pragma unroll
  for (int q=0;q<4;q++){
    float4 hv = ((const float4*)hp)[q];
    h[4*q]=hv.x; h[4*q+1]=hv.y; h[4*q+2]=hv.z; h[4*q+3]=hv.w;
  }
  int l0 = c*LCH;
  const float* drow = delta + ((size_t)(b*LSEQ + l0))*DINNER + d;
  const float* urow = u     + ((size_t)(b*LSEQ + l0))*DINNER + d;
  const float* rrow = xz    + ((size_t)(b*LSEQ + l0))*2*DINNER + DINNER + d;
  const float* xrow = xdbl  + ((size_t)(b*LSEQ + l0))*96 + DTRANK;
  bf16_t* yrow = ysb + ((size_t)(b*LSEQ + l0))*DINNER + d;
  for (int l=0; l<LCH; ++l) {
    float dv = drow[(size_t)l*DINNER];
    float uv = urow[(size_t)l*DINNER];
    float rv = rrow[(size_t)l*2*DINNER];
    const float* bc = xrow + l*96;            // B at [0..15], C at [16..31]
    float du = dv*uv;
    float y = 0.f;
    #pragma unroll
    for (int s=0;s<DSTATE;s++){
      float dA = __expf(dv*A[s]);
      h[s] = dA*h[s] + du*bc[s];
      y += h[s]*bc[DSTATE+s];
    }
    y = (y + uv*Dpd) * (rv * sigmoidf_(rv));
    yrow[(size_t)l*DINNER] = (bf16_t)y;
  }
}

extern "C" void kernel_launch(void* const* d_in, const int* in_sizes, int n_in,
                              void* d_out, int out_size, void* d_ws, size_t ws_size,
                              hipStream_t stream)
{
  const float* x      = (const float*)d_in[0];
  const float* ln_g   = (const float*)d_in[1];
  const float* ln_b   = (const float*)d_in[2];
  const float* in_w   = (const float*)d_in[3];
  const float* conv_w = (const float*)d_in[4];
  const float* conv_b = (const float*)d_in[5];
  const float* xp_w   = (const float*)d_in[6];
  const float* dt_w   = (const float*)d_in[7];
  const float* dt_b   = (const float*)d_in[8];
  const float* A_log  = (const float*)d_in[9];
  const float* Dp     = (const float*)d_in[10];
  const float* out_w  = (const float*)d_in[11];
  const float* fn_g   = (const float*)d_in[12];
  const float* fn_b   = (const float*)d_in[13];
  float* out = (float*)d_out;

  char* p = (char*)d_ws;
  auto alloc = [&](size_t bytes)->char*{ char* r = p; p += (bytes + 255) & ~(size_t)255; return r; };

  const size_t N_INW = (size_t)2*2*DINNER*DMODEL;   // 8.4M
  const size_t N_XPW = (size_t)2*96*DINNER;
  const size_t N_DTW = (size_t)2*DINNER*DTRANK;
  const size_t N_OUTW= (size_t)2*DMODEL*DINNER;

  bf16_t* inw_b  = (bf16_t*)alloc(N_INW*2);
  bf16_t* xpw_b  = (bf16_t*)alloc(N_XPW*2);
  bf16_t* dtw_b  = (bf16_t*)alloc(N_DTW*2);
  bf16_t* outw_b = (bf16_t*)alloc(N_OUTW*2);
  float*  x_cur  = (float*) alloc((size_t)ROWS*DMODEL*4);
  bf16_t* xn_b   = (bf16_t*)alloc((size_t)ROWS*DMODEL*2);
  float*  xz     = (float*) alloc((size_t)ROWS*2*DINNER*4);
  float*  ubuf   = (float*) alloc((size_t)ROWS*DINNER*4);
  bf16_t* ub_b   = (bf16_t*)alloc((size_t)ROWS*DINNER*2);   // reused as ys_b
  float*  xdbl   = (float*) alloc((size_t)ROWS*96*4);
  bf16_t* xdbl_b = (bf16_t*)alloc((size_t)ROWS*96*2);
  float*  delta  = (float*) alloc((size_t)ROWS*DINNER*4);
  float*  hout   = (float*) alloc((size_t)NB*NCH*DINNER*DSTATE*4);
  float*  sumd   = (float*) alloc((size_t)NB*NCH*DINNER*4);
  bf16_t* ys_b   = ub_b;   // x_proj consumes ub_b before phase3 writes ys

  // weight conversion (same work every call)
  cvt_kernel<<<(int)((N_INW/4 +255)/256),256,0,stream>>>(in_w,  inw_b,  (int)(N_INW/4));
  cvt_kernel<<<(int)((N_XPW/4 +255)/256),256,0,stream>>>(xp_w,  xpw_b,  (int)(N_XPW/4));
  cvt_kernel<<<(int)((N_DTW/4 +255)/256),256,0,stream>>>(dt_w,  dtw_b,  (int)(N_DTW/4));
  cvt_kernel<<<(int)((N_OUTW/4+255)/256),256,0,stream>>>(out_w, outw_b, (int)(N_OUTW/4));

  for (int layer=0; layer<2; ++layer) {
    const float* xin = (layer==0) ? x : x_cur;
    const float* Al  = A_log + (size_t)layer*DINNER*DSTATE;
    ln_kernel<1><<<ROWS,256,0,stream>>>(xin, ln_g+layer*DMODEL, ln_b+layer*DMODEL, nullptr, xn_b);
    // xz = xn @ in_w^T   [2048 x 4096], K=1024
    gemm_bf16<0,false><<<dim3(2*DINNER/GBN, ROWS/GBM),256,0,stream>>>(
        xn_b, DMODEL, inw_b + (size_t)layer*2*DINNER*DMODEL, DMODEL,
        xz, 2*DINNER, ROWS, 2*DINNER, DMODEL, nullptr, nullptr, nullptr);
    // u = silu(conv(xz[:, :2048]) + cb)  (fp32 + bf16)
    conv_silu_kernel<<<(ROWS*DINNER)/256,256,0,stream>>>(
        xz, conv_w + (size_t)layer*DINNER*4, conv_b + (size_t)layer*DINNER, ubuf, ub_b);
    // xdbl = u @ xp_w^T   [2048 x 96], K=2048  (fp32 + bf16 dual write, N-guarded)
    gemm_bf16<3,true><<<dim3(1, ROWS/GBM),256,0,stream>>>(
        ub_b, DINNER, xpw_b + (size_t)layer*96*DINNER, DINNER,
        xdbl, 96, ROWS, 96, DINNER, nullptr, nullptr, xdbl_b);
    // delta = softplus(xdbl[:, :64] @ dt_w^T + dt_b)   [2048 x 2048], K=64
    gemm_bf16<1,false><<<dim3(DINNER/GBN, ROWS/GBM),256,0,stream>>>(
        xdbl_b, 96, dtw_b + (size_t)layer*DINNER*DTRANK, DTRANK,
        delta, DINNER, ROWS, DINNER, DTRANK,
        dt_b + (size_t)layer*DINNER, nullptr, nullptr);
    // chunked selective scan; phase3 writes ys as bf16 (over ub_b, already consumed)
    scan_phase1<<<(NB*NCH*DINNER)/256,256,0,stream>>>(delta, ubuf, xdbl, Al, hout, sumd);
    scan_phase2<<<(NB*DINNER*DSTATE)/256,256,0,stream>>>(hout, sumd, Al);
    scan_phase3<<<(NB*NCH*DINNER)/256,256,0,stream>>>(
        delta, ys_b, ubuf, xz, xdbl, Al, Dp + (size_t)layer*DINNER, hout);
    // x_cur = xin + ys @ out_w^T   [2048 x 1024], K=2048
    gemm_bf16<2,false><<<dim3(DMODEL/GBN, ROWS/GBM),256,0,stream>>>(
        ys_b, DINNER, outw_b + (size_t)layer*DMODEL*DINNER, DINNER,
        x_cur, DMODEL, ROWS, DMODEL, DINNER, nullptr, xin, nullptr);
  }
  ln_kernel<0><<<ROWS,256,0,stream>>>(x_cur, fn_g, fn_b, out, nullptr);
}